// Round 11
// baseline (358.599 us; speedup 1.0000x reference)
//
#include <hip/hip_runtime.h>

// TemporalGCN: 2-layer GCN (gcn_norm, self-loops) + linear head.
// N=100000, E=1.6M, dims 128->64->64->16.
//
// R2:  fp32-atomic push scatter = TCC atomic-rate bound (400MB WRITE/layer).
// R3:  CSR+pull = 555us; bucket = scattered-4B-write bound (134us, 64B lines).
// R4:  LDS-accumulate agg regressed 7x (wave-serial latency chain).
// R6:  passB w/ few global cursors = atomic-contention bound (377us).
// R7:  block-staged passB = 400us; fp32 gemm1 (LDS-issue bound) tops.
// R8:  fp16 MFMA GEMMs = 330us; pull tops (72us x2).
// R9:  shfl-broadcast indices = 308us; pull 59.6us.
// R10: 4 edges/wave-load = 294us; pull 53.5us. FETCH unchanged 158MB,
//      fetch+write rate pinned ~3.5TB/s -> pull is at the random-access
//      fabric-traffic roofline; only lever left is BYTES.
// R11: (a) split-feature pull: two half-passes, working set 6.4MB of 64B
//      lines (vs 12.8) -> higher per-XCD L2 hit; 8 edges per wave-load.
//      (b) a1/a2 in fp16 (halves the 104MB a-round-trip).
//      (c) merge prep+cscan. Pre-commit: if half-pull FETCH ~110MB each,
//      lines are 128B non-sectored -> revert split, declare roofline.

constexpr int ID = 128;   // input dim
constexpr int HD = 64;    // hidden dim
constexpr int OD = 16;    // output dim
constexpr int RB = 512;   // nodes per coarse bucket
constexpr int KMAX = 256; // max buckets (K = ceil(N/RB) = 196)
constexpr int CHUNK = 4096;

typedef _Float16 f16x8 __attribute__((ext_vector_type(8)));
typedef _Float16 f16x4 __attribute__((ext_vector_type(4)));
typedef float    f32x4 __attribute__((ext_vector_type(4)));

// ---- pass A: coarse histogram of dst>>9 ----
__global__ __launch_bounds__(256) void passA_kernel(const int4* __restrict__ dst4,
                                                    int* __restrict__ cnt, int E4, int K) {
    __shared__ int h[KMAX];
    int tid = threadIdx.x;
    for (int i = tid; i < K; i += 256) h[i] = 0;
    __syncthreads();
    int id = blockIdx.x * 256 + tid, n = gridDim.x * 256;
    for (int i = id; i < E4; i += n) {
        int4 d = dst4[i];
        atomicAdd(&h[d.x >> 9], 1); atomicAdd(&h[d.y >> 9], 1);
        atomicAdd(&h[d.z >> 9], 1); atomicAdd(&h[d.w >> 9], 1);
    }
    __syncthreads();
    for (int i = tid; i < K; i += 256) if (h[i]) atomicAdd(&cnt[i], h[i]);
}

// ---- merged: blocks 0-31 transpose weights to fp16 [n][k]; block 32 does
// the coarse scan cnt[K] -> coff[K+1], cursor[K] ----
__global__ __launch_bounds__(256) void prepscan_kernel(
    const float* __restrict__ W1, const float* __restrict__ W2,
    _Float16* __restrict__ w1t, _Float16* __restrict__ w2t,
    const int* __restrict__ cnt, int* __restrict__ coff,
    int* __restrict__ cursor, int K, int E) {
    int tid = threadIdx.x;
    if (blockIdx.x < 32) {
        int id = blockIdx.x * 256 + tid, n = 32 * 256;
        for (int i = id; i < ID * HD; i += n) {   // W1 [128][64] -> w1t [64][128]
            int k = i >> 6, c = i & 63;
            w1t[c * ID + k] = (_Float16)W1[i];
        }
        for (int i = id; i < HD * HD; i += n) {   // W2 [64][64] -> w2t [64][64]
            int k = i >> 6, c = i & 63;
            w2t[c * HD + k] = (_Float16)W2[i];
        }
    } else {
        __shared__ int ts[KMAX];
        int v = (tid < K) ? cnt[tid] : 0;
        ts[tid] = v; __syncthreads();
        for (int d = 1; d < KMAX; d <<= 1) {
            int t = (tid >= d) ? ts[tid - d] : 0;
            __syncthreads();
            ts[tid] += t;
            __syncthreads();
        }
        if (tid < K) { int excl = ts[tid] - v; coff[tid] = excl; cursor[tid] = excl; }
        if (tid == 0) coff[K] = E;
    }
}

// ---- pass B (block-staged): chunk -> LDS histogram -> one global atomicAdd
// per (chunk,bucket) -> LDS reorder -> bucket-grouped coalesced writeout.
__global__ __launch_bounds__(256) void passB_kernel(const int* __restrict__ src,
                                                    const int* __restrict__ dst,
                                                    int* __restrict__ cursor,
                                                    unsigned* __restrict__ epk, int E) {
    __shared__ unsigned      buf[CHUNK];      // 16 KB  reordered payloads
    __shared__ unsigned char bkt[CHUNK];      //  4 KB  bucket of each slot
    __shared__ int hist[KMAX], lofs[KMAX], gpos[KMAX], ts[KMAX];
    int tid = threadIdx.x;
    int base = blockIdx.x * CHUNK;
    int cnt = min(CHUNK, E - base);

    for (int i = tid; i < KMAX; i += 256) hist[i] = 0;
    __syncthreads();

    unsigned mypay[CHUNK / 256];
    short    myb[CHUNK / 256];
    short    myrank[CHUNK / 256];
    #pragma unroll
    for (int j = 0; j < CHUNK / 256; ++j) {
        int o = j * 256 + tid;
        myb[j] = -1;
        if (o < cnt) {
            int d = dst[base + o], s = src[base + o];
            int b = d >> 9;
            myb[j] = (short)b;
            myrank[j] = (short)atomicAdd(&hist[b], 1);
            mypay[j] = ((unsigned)(d & (RB - 1)) << 17) | (unsigned)s;
        }
    }
    __syncthreads();

    int v = hist[tid];
    ts[tid] = v; __syncthreads();
    for (int d = 1; d < KMAX; d <<= 1) {
        int t = (tid >= d) ? ts[tid - d] : 0;
        __syncthreads();
        ts[tid] += t;
        __syncthreads();
    }
    lofs[tid] = ts[tid] - v;
    if (v > 0) gpos[tid] = atomicAdd(&cursor[tid], v);
    __syncthreads();

    #pragma unroll
    for (int j = 0; j < CHUNK / 256; ++j) {
        if (myb[j] >= 0) {
            int pos = lofs[myb[j]] + myrank[j];
            buf[pos] = mypay[j];
            bkt[pos] = (unsigned char)myb[j];
        }
    }
    __syncthreads();

    for (int i = tid; i < cnt; i += 256) {
        int b = bkt[i];
        epk[gpos[b] + (i - lofs[b])] = buf[i];
    }
}

// ---- per-bucket sort -> exact CSR (off, sse) + dinv ----
__global__ __launch_bounds__(512) void sortB_kernel(
    const int* __restrict__ coff, const unsigned* __restrict__ epk,
    int* __restrict__ sse, int* __restrict__ off,
    float* __restrict__ dinv, int N) {
    __shared__ int hist[RB];
    __shared__ int lofs[RB];
    __shared__ int ts[RB];
    int b = blockIdx.x, tid = threadIdx.x, base = b * RB;
    hist[tid] = 0;
    __syncthreads();
    int e0 = coff[b], e1 = coff[b + 1];
    for (int e = e0 + tid; e < e1; e += 512)
        atomicAdd(&hist[epk[e] >> 17], 1);
    __syncthreads();
    int v = hist[tid];
    ts[tid] = v; __syncthreads();
    for (int d = 1; d < RB; d <<= 1) {
        int t = (tid >= d) ? ts[tid - d] : 0;
        __syncthreads();
        ts[tid] += t;
        __syncthreads();
    }
    {
        int excl = ts[tid] - v;
        int node = base + tid;
        if (node <= N) off[node] = e0 + excl;
        if (node < N)  dinv[node] = rsqrtf((float)v + 1.0f);
        lofs[tid] = e0 + excl;
    }
    __syncthreads();
    for (int e = e0 + tid; e < e1; e += 512) {
        unsigned pk = epk[e];
        int pos = atomicAdd(&lofs[pk >> 17], 1);
        sse[pos] = (int)(pk & 0x1FFFF);
    }
}

// ---- GEMM1 (MFMA): th = fp16( (x @ W1) * dinv[row] )  [N,128]x[128,64] ----
__global__ __launch_bounds__(256) void gemm1_kernel(
    const float* __restrict__ x, const _Float16* __restrict__ w1t,
    const float* __restrict__ dinv, _Float16* __restrict__ th, int N) {
    __shared__ __align__(16) _Float16 xh[64 * ID];  // 16 KB, swizzled
    __shared__ __align__(16) _Float16 wh[HD * ID];  // 16 KB, swizzled
    int tid = threadIdx.x;
    int base = blockIdx.x * 64;
    #pragma unroll
    for (int it = 0; it < 4; ++it) {
        int idx = (it * 256 + tid) * 8;       // 0..8191 step 8
        int r = idx >> 7, c = idx & 127;
        f16x8 v = *(const f16x8*)&w1t[idx];
        *(f16x8*)&wh[r * ID + (c ^ ((r & 7) << 3))] = v;
    }
    #pragma unroll
    for (int it = 0; it < 4; ++it) {
        int idx = (it * 256 + tid) * 8;
        int r = idx >> 7, c = idx & 127;
        int row = base + r;
        f16x8 h;
        if (row < N) {
            float4 a = *(const float4*)&x[(size_t)row * ID + c];
            float4 b = *(const float4*)&x[(size_t)row * ID + c + 4];
            h[0] = (_Float16)a.x; h[1] = (_Float16)a.y;
            h[2] = (_Float16)a.z; h[3] = (_Float16)a.w;
            h[4] = (_Float16)b.x; h[5] = (_Float16)b.y;
            h[6] = (_Float16)b.z; h[7] = (_Float16)b.w;
        } else {
            #pragma unroll
            for (int j = 0; j < 8; ++j) h[j] = (_Float16)0.f;
        }
        *(f16x8*)&xh[r * ID + (c ^ ((r & 7) << 3))] = h;
    }
    __syncthreads();
    int lane = tid & 63, wv = tid >> 6;       // 4 waves; wave = 16 rows
    int lr = lane & 15, g = lane >> 4;
    f32x4 z = {0.f, 0.f, 0.f, 0.f};
    f32x4 acc[4] = {z, z, z, z};
    #pragma unroll
    for (int kk = 0; kk < 4; ++kk) {          // K = 128, 32 per step
        int kb = kk * 32 + g * 8;
        int ar = wv * 16 + lr;
        f16x8 af = *(const f16x8*)&xh[ar * ID + (kb ^ ((ar & 7) << 3))];
        #pragma unroll
        for (int ct = 0; ct < 4; ++ct) {
            int br = ct * 16 + lr;
            f16x8 bf = *(const f16x8*)&wh[br * ID + (kb ^ ((br & 7) << 3))];
            acc[ct] = __builtin_amdgcn_mfma_f32_16x16x32_f16(af, bf, acc[ct], 0, 0, 0);
        }
    }
    int r0 = base + wv * 16 + g * 4;
    #pragma unroll
    for (int j = 0; j < 4; ++j) {
        int row = r0 + j;
        if (row < N) {
            float dd = dinv[row];
            #pragma unroll
            for (int ct = 0; ct < 4; ++ct)
                th[(size_t)row * HD + ct * 16 + lr] = (_Float16)(acc[ct][j] * dd);
        }
    }
}

// ---- half-pull: one wave per node, 32 features (one half-row) per pass.
// 8 edges per wave-load (8 lanes x 8B). th is dinv-premultiplied:
// a[d] = dinv[d] * ( sum_{s in N(d)} th'[s] + th'[d] ), a stored fp16.
__global__ __launch_bounds__(256) void pull_half_kernel(
    const int* __restrict__ off, const int* __restrict__ sse,
    const float* __restrict__ dinv, const _Float16* __restrict__ th,
    _Float16* __restrict__ a, int N, int half) {
    int lane = threadIdx.x & 63;
    int w = (blockIdx.x * blockDim.x + threadIdx.x) >> 6;
    if (w >= N) return;
    int sub = lane >> 3;          // 0..7: edge slot within a load group
    int fl  = lane & 7;           // feature quad within the half
    const f16x4* th4 = (const f16x4*)th;    // row = 16 quads; half -> +8
    size_t hoff = (size_t)(half << 3) + fl;
    int o0 = off[w], o1 = off[w + 1];
    float ax = 0.f, ay = 0.f, az = 0.f, aw = 0.f;
    int j = o0;
    while (j < o1) {
        int nb = min(64, o1 - j);
        int sidx = (lane < nb) ? sse[j + lane] : 0;   // one coalesced load
        int i = 0;
        for (; i + 31 < nb; i += 32) {                // 32 edges / iter, 4 loads
            int s0 = __shfl(sidx, i + sub);
            int s1 = __shfl(sidx, i + 8 + sub);
            int s2 = __shfl(sidx, i + 16 + sub);
            int s3 = __shfl(sidx, i + 24 + sub);
            f16x4 v0 = th4[(size_t)s0 * 16 + hoff];
            f16x4 v1 = th4[(size_t)s1 * 16 + hoff];
            f16x4 v2 = th4[(size_t)s2 * 16 + hoff];
            f16x4 v3 = th4[(size_t)s3 * 16 + hoff];
            ax += ((float)v0[0] + (float)v1[0]) + ((float)v2[0] + (float)v3[0]);
            ay += ((float)v0[1] + (float)v1[1]) + ((float)v2[1] + (float)v3[1]);
            az += ((float)v0[2] + (float)v1[2]) + ((float)v2[2] + (float)v3[2]);
            aw += ((float)v0[3] + (float)v1[3]) + ((float)v2[3] + (float)v3[3]);
        }
        for (; i + 15 < nb; i += 16) {                // 16 edges / iter, 2 loads
            int s0 = __shfl(sidx, i + sub);
            int s1 = __shfl(sidx, i + 8 + sub);
            f16x4 v0 = th4[(size_t)s0 * 16 + hoff];
            f16x4 v1 = th4[(size_t)s1 * 16 + hoff];
            ax += (float)v0[0] + (float)v1[0];
            ay += (float)v0[1] + (float)v1[1];
            az += (float)v0[2] + (float)v1[2];
            aw += (float)v0[3] + (float)v1[3];
        }
        for (; i < nb; i += 8) {                      // tail (predicated)
            int e = i + sub;
            int s = __shfl(sidx, (e < nb) ? e : (nb - 1));
            if (e < nb) {
                f16x4 v = th4[(size_t)s * 16 + hoff];
                ax += (float)v[0]; ay += (float)v[1];
                az += (float)v[2]; aw += (float)v[3];
            }
        }
        j += nb;
    }
    // butterfly over the 8 sub-slots (lanes fl, fl+8, ..., fl+56)
    ax += __shfl_xor(ax, 8); ax += __shfl_xor(ax, 16); ax += __shfl_xor(ax, 32);
    ay += __shfl_xor(ay, 8); ay += __shfl_xor(ay, 16); ay += __shfl_xor(ay, 32);
    az += __shfl_xor(az, 8); az += __shfl_xor(az, 16); az += __shfl_xor(az, 32);
    aw += __shfl_xor(aw, 8); aw += __shfl_xor(aw, 16); aw += __shfl_xor(aw, 32);
    if (sub == 0) {
        f16x4 sv = th4[(size_t)w * 16 + hoff];        // self-term
        float dd = dinv[w];
        f16x4 o;
        o[0] = (_Float16)(dd * (ax + (float)sv[0]));
        o[1] = (_Float16)(dd * (ay + (float)sv[1]));
        o[2] = (_Float16)(dd * (az + (float)sv[2]));
        o[3] = (_Float16)(dd * (aw + (float)sv[3]));
        ((f16x4*)a)[(size_t)w * 16 + hoff] = o;       // 8 lanes x 8B = 64B
    }
}

// ---- GEMM2 (MFMA): th = fp16( (relu(a1+b1) @ W2) * dinv[row] ), a1 fp16 ----
__global__ __launch_bounds__(256) void gemm2_kernel(
    const _Float16* __restrict__ ain, const _Float16* __restrict__ w2t,
    const float* __restrict__ bias, const float* __restrict__ dinv,
    _Float16* __restrict__ th, int N) {
    __shared__ __align__(16) _Float16 ah[64 * HD];  // 8 KB, swizzled
    __shared__ __align__(16) _Float16 wh[HD * HD];  // 8 KB, swizzled
    int tid = threadIdx.x;
    int base = blockIdx.x * 64;
    #pragma unroll
    for (int it = 0; it < 2; ++it) {
        int idx = (it * 256 + tid) * 8;       // 0..4095 step 8
        int r = idx >> 6, c = idx & 63;
        f16x8 v = *(const f16x8*)&w2t[idx];
        *(f16x8*)&wh[r * HD + (c ^ ((r & 7) << 3))] = v;
    }
    #pragma unroll
    for (int it = 0; it < 2; ++it) {
        int idx = (it * 256 + tid) * 8;
        int r = idx >> 6, c = idx & 63;
        int row = base + r;
        f16x8 h;
        if (row < N) {
            f16x8 v = *(const f16x8*)&ain[(size_t)row * HD + c];
            #pragma unroll
            for (int jj = 0; jj < 8; ++jj)
                h[jj] = (_Float16)fmaxf((float)v[jj] + bias[c + jj], 0.f);
        } else {
            #pragma unroll
            for (int jj = 0; jj < 8; ++jj) h[jj] = (_Float16)0.f;
        }
        *(f16x8*)&ah[r * HD + (c ^ ((r & 7) << 3))] = h;
    }
    __syncthreads();
    int lane = tid & 63, wv = tid >> 6;
    int lr = lane & 15, g = lane >> 4;
    f32x4 z = {0.f, 0.f, 0.f, 0.f};
    f32x4 acc[4] = {z, z, z, z};
    #pragma unroll
    for (int kk = 0; kk < 2; ++kk) {          // K = 64, 32 per step
        int kb = kk * 32 + g * 8;
        int ar = wv * 16 + lr;
        f16x8 af = *(const f16x8*)&ah[ar * HD + (kb ^ ((ar & 7) << 3))];
        #pragma unroll
        for (int ct = 0; ct < 4; ++ct) {
            int br = ct * 16 + lr;
            f16x8 bf = *(const f16x8*)&wh[br * HD + (kb ^ ((br & 7) << 3))];
            acc[ct] = __builtin_amdgcn_mfma_f32_16x16x32_f16(af, bf, acc[ct], 0, 0, 0);
        }
    }
    int r0 = base + wv * 16 + g * 4;
    #pragma unroll
    for (int j = 0; j < 4; ++j) {
        int row = r0 + j;
        if (row < N) {
            float dd = dinv[row];
            #pragma unroll
            for (int ct = 0; ct < 4; ++ct)
                th[(size_t)row * HD + ct * 16 + lr] = (_Float16)(acc[ct][j] * dd);
        }
    }
}

// ---- head: out = (a2 + b2) @ Wc + bc   [N,64]x[64,16], a2 fp16 ----
__global__ __launch_bounds__(256) void final_kernel(
    const _Float16* __restrict__ ain, const float* __restrict__ b2,
    const float* __restrict__ Wc, const float* __restrict__ bc,
    float* __restrict__ out, int N) {
    __shared__ float Ws[HD * OD];     // 4 KB
    __shared__ float hs[16][HD + 1];  // padded
    int tid = threadIdx.x;
    for (int i = tid; i < HD * OD; i += 256) Ws[i] = Wc[i];
    int base = blockIdx.x * 16;
    for (int i = tid; i < 128; i += 256) {       // 16 rows x 8 f16x8 chunks
        int r = i >> 3, c = (i & 7) * 8;
        int row = base + r;
        if (row < N) {
            f16x8 v = *(const f16x8*)&ain[(size_t)row * HD + c];
            #pragma unroll
            for (int jj = 0; jj < 8; ++jj)
                hs[r][c + jj] = (float)v[jj] + b2[c + jj];
        } else {
            #pragma unroll
            for (int jj = 0; jj < 8; ++jj) hs[r][c + jj] = 0.f;
        }
    }
    __syncthreads();
    int col = tid & 15, r = tid >> 4;
    int row = base + r;
    if (row < N) {
        float acc = bc[col];
        #pragma unroll
        for (int k = 0; k < HD; ++k)
            acc += hs[r][k] * Ws[k * OD + col];
        out[(size_t)row * OD + col] = acc;
    }
}

extern "C" void kernel_launch(void* const* d_in, const int* in_sizes, int n_in,
                              void* d_out, int out_size, void* d_ws, size_t ws_size,
                              hipStream_t stream) {
    const float* x  = (const float*)d_in[0];
    const int*   ei = (const int*)d_in[1];   // [2,E] flat int32
    const float* W1 = (const float*)d_in[2];
    const float* b1 = (const float*)d_in[3];
    const float* W2 = (const float*)d_in[4];
    const float* b2 = (const float*)d_in[5];
    const float* Wc = (const float*)d_in[6];
    const float* bc = (const float*)d_in[7];
    float* out = (float*)d_out;

    int N = in_sizes[0] / ID;   // 100000
    int E = in_sizes[1] / 2;    // 1600000 (multiple of 4)
    const int* src = ei;
    const int* dst = ei + E;
    int K = (N + RB - 1) / RB;  // 196 coarse buckets (K <= KMAX)
    int Npad = (N + 63) & ~63;

    char* p = (char*)d_ws;
    int*      cnt    = (int*)p;      p += KMAX * 4;
    int*      coff   = (int*)p;      p += (KMAX + 4) * 4;
    int*      cursor = (int*)p;      p += KMAX * 4;
    float*    dinv   = (float*)p;    p += (size_t)Npad * 4;
    int*      off    = (int*)p;      p += (size_t)(Npad + RB) * 4;
    _Float16* w1t    = (_Float16*)p; p += (size_t)HD * ID * 2;  // [64][128]
    _Float16* w2t    = (_Float16*)p; p += (size_t)HD * HD * 2;  // [64][64]
    unsigned* epk    = (unsigned*)p; p += (size_t)E * 4;        // bucketed edges
    int*      sse    = (int*)p;      p += (size_t)E * 4;        // CSR src
    _Float16* th     = (_Float16*)p; p += (size_t)N * HD * 2;   // dinv-premult msgs
    _Float16* a1     = (_Float16*)p; p += (size_t)N * HD * 2;   // agg out, fp16

    hipMemsetAsync(cnt, 0, (size_t)K * sizeof(int), stream);

    // dense CSR build (shared by both layers) + weight prep
    passA_kernel<<<512, 256, 0, stream>>>((const int4*)dst, cnt, E / 4, K);
    prepscan_kernel<<<33, 256, 0, stream>>>(W1, W2, w1t, w2t, cnt, coff, cursor, K, E);
    passB_kernel<<<(E + CHUNK - 1) / CHUNK, 256, 0, stream>>>(src, dst, cursor, epk, E);
    sortB_kernel<<<K, RB, 0, stream>>>(coff, epk, sse, off, dinv, N);

    int pgrid = (N * 64 + 255) / 256;

    // layer 1
    gemm1_kernel<<<(N + 63) / 64, 256, 0, stream>>>(x, w1t, dinv, th, N);
    pull_half_kernel<<<pgrid, 256, 0, stream>>>(off, sse, dinv, th, a1, N, 0);
    pull_half_kernel<<<pgrid, 256, 0, stream>>>(off, sse, dinv, th, a1, N, 1);

    // layer 2
    gemm2_kernel<<<(N + 63) / 64, 256, 0, stream>>>(a1, w2t, b1, dinv, th, N);
    pull_half_kernel<<<pgrid, 256, 0, stream>>>(off, sse, dinv, th, a1, N, 0);
    pull_half_kernel<<<pgrid, 256, 0, stream>>>(off, sse, dinv, th, a1, N, 1);

    // head
    final_kernel<<<(N + 15) / 16, 256, 0, stream>>>(a1, b2, Wc, bc, out, N);
}

// Round 12
// 288.665 us; speedup vs baseline: 1.2423x; 1.2423x over previous
//
#include <hip/hip_runtime.h>

// TemporalGCN: 2-layer GCN (gcn_norm, self-loops) + linear head.
// N=100000, E=1.6M, dims 128->64->64->16.
//
// R2:  fp32-atomic push scatter = TCC atomic-rate bound.
// R3:  CSR+pull = 555us; bucket = scattered-4B-write bound.
// R4:  LDS-accumulate agg regressed 7x (wave-serial latency chain).
// R6:  passB w/ few global cursors = atomic-contention bound.
// R7:  block-staged passB = 400us; fp32 gemm1 (LDS-issue bound) tops.
// R8:  fp16 MFMA GEMMs = 330us.
// R9:  shfl-broadcast indices = 308us.
// R10: 4 edges/wave-load = 294us; pull pinned at ~3.5TB/s random-line rate.
// R11: split-feature pull REGRESSED (359us): half-pull FETCH 155.8MB = full,
//      -> TCC lines are 128B non-sectored; feature-splitting doubles traffic.
// R12: revert to R10 full-row pull; keep fp16 a1/a2 (pull WRITE 26->13MB,
//      gemm2/final FETCH halved) + merged prepscan. Pull is at its
//      L2-capacity/random-line roofline (FETCH ~= capacity-model floor).

constexpr int ID = 128;   // input dim
constexpr int HD = 64;    // hidden dim
constexpr int OD = 16;    // output dim
constexpr int RB = 512;   // nodes per coarse bucket
constexpr int KMAX = 256; // max buckets (K = ceil(N/RB) = 196)
constexpr int CHUNK = 4096;

typedef _Float16 f16x8 __attribute__((ext_vector_type(8)));
typedef _Float16 f16x4 __attribute__((ext_vector_type(4)));
typedef float    f32x4 __attribute__((ext_vector_type(4)));

// ---- pass A: coarse histogram of dst>>9 ----
__global__ __launch_bounds__(256) void passA_kernel(const int4* __restrict__ dst4,
                                                    int* __restrict__ cnt, int E4, int K) {
    __shared__ int h[KMAX];
    int tid = threadIdx.x;
    for (int i = tid; i < K; i += 256) h[i] = 0;
    __syncthreads();
    int id = blockIdx.x * 256 + tid, n = gridDim.x * 256;
    for (int i = id; i < E4; i += n) {
        int4 d = dst4[i];
        atomicAdd(&h[d.x >> 9], 1); atomicAdd(&h[d.y >> 9], 1);
        atomicAdd(&h[d.z >> 9], 1); atomicAdd(&h[d.w >> 9], 1);
    }
    __syncthreads();
    for (int i = tid; i < K; i += 256) if (h[i]) atomicAdd(&cnt[i], h[i]);
}

// ---- merged: blocks 0-31 transpose weights to fp16 [n][k]; block 32 does
// the coarse scan cnt[K] -> coff[K+1], cursor[K] ----
__global__ __launch_bounds__(256) void prepscan_kernel(
    const float* __restrict__ W1, const float* __restrict__ W2,
    _Float16* __restrict__ w1t, _Float16* __restrict__ w2t,
    const int* __restrict__ cnt, int* __restrict__ coff,
    int* __restrict__ cursor, int K, int E) {
    int tid = threadIdx.x;
    if (blockIdx.x < 32) {
        int id = blockIdx.x * 256 + tid, n = 32 * 256;
        for (int i = id; i < ID * HD; i += n) {   // W1 [128][64] -> w1t [64][128]
            int k = i >> 6, c = i & 63;
            w1t[c * ID + k] = (_Float16)W1[i];
        }
        for (int i = id; i < HD * HD; i += n) {   // W2 [64][64] -> w2t [64][64]
            int k = i >> 6, c = i & 63;
            w2t[c * HD + k] = (_Float16)W2[i];
        }
    } else {
        __shared__ int ts[KMAX];
        int v = (tid < K) ? cnt[tid] : 0;
        ts[tid] = v; __syncthreads();
        for (int d = 1; d < KMAX; d <<= 1) {
            int t = (tid >= d) ? ts[tid - d] : 0;
            __syncthreads();
            ts[tid] += t;
            __syncthreads();
        }
        if (tid < K) { int excl = ts[tid] - v; coff[tid] = excl; cursor[tid] = excl; }
        if (tid == 0) coff[K] = E;
    }
}

// ---- pass B (block-staged): chunk -> LDS histogram -> one global atomicAdd
// per (chunk,bucket) -> LDS reorder -> bucket-grouped coalesced writeout.
__global__ __launch_bounds__(256) void passB_kernel(const int* __restrict__ src,
                                                    const int* __restrict__ dst,
                                                    int* __restrict__ cursor,
                                                    unsigned* __restrict__ epk, int E) {
    __shared__ unsigned      buf[CHUNK];      // 16 KB  reordered payloads
    __shared__ unsigned char bkt[CHUNK];      //  4 KB  bucket of each slot
    __shared__ int hist[KMAX], lofs[KMAX], gpos[KMAX], ts[KMAX];
    int tid = threadIdx.x;
    int base = blockIdx.x * CHUNK;
    int cnt = min(CHUNK, E - base);

    for (int i = tid; i < KMAX; i += 256) hist[i] = 0;
    __syncthreads();

    unsigned mypay[CHUNK / 256];
    short    myb[CHUNK / 256];
    short    myrank[CHUNK / 256];
    #pragma unroll
    for (int j = 0; j < CHUNK / 256; ++j) {
        int o = j * 256 + tid;
        myb[j] = -1;
        if (o < cnt) {
            int d = dst[base + o], s = src[base + o];
            int b = d >> 9;
            myb[j] = (short)b;
            myrank[j] = (short)atomicAdd(&hist[b], 1);
            mypay[j] = ((unsigned)(d & (RB - 1)) << 17) | (unsigned)s;
        }
    }
    __syncthreads();

    int v = hist[tid];
    ts[tid] = v; __syncthreads();
    for (int d = 1; d < KMAX; d <<= 1) {
        int t = (tid >= d) ? ts[tid - d] : 0;
        __syncthreads();
        ts[tid] += t;
        __syncthreads();
    }
    lofs[tid] = ts[tid] - v;
    if (v > 0) gpos[tid] = atomicAdd(&cursor[tid], v);
    __syncthreads();

    #pragma unroll
    for (int j = 0; j < CHUNK / 256; ++j) {
        if (myb[j] >= 0) {
            int pos = lofs[myb[j]] + myrank[j];
            buf[pos] = mypay[j];
            bkt[pos] = (unsigned char)myb[j];
        }
    }
    __syncthreads();

    for (int i = tid; i < cnt; i += 256) {
        int b = bkt[i];
        epk[gpos[b] + (i - lofs[b])] = buf[i];
    }
}

// ---- per-bucket sort -> exact CSR (off, sse) + dinv ----
__global__ __launch_bounds__(512) void sortB_kernel(
    const int* __restrict__ coff, const unsigned* __restrict__ epk,
    int* __restrict__ sse, int* __restrict__ off,
    float* __restrict__ dinv, int N) {
    __shared__ int hist[RB];
    __shared__ int lofs[RB];
    __shared__ int ts[RB];
    int b = blockIdx.x, tid = threadIdx.x, base = b * RB;
    hist[tid] = 0;
    __syncthreads();
    int e0 = coff[b], e1 = coff[b + 1];
    for (int e = e0 + tid; e < e1; e += 512)
        atomicAdd(&hist[epk[e] >> 17], 1);
    __syncthreads();
    int v = hist[tid];
    ts[tid] = v; __syncthreads();
    for (int d = 1; d < RB; d <<= 1) {
        int t = (tid >= d) ? ts[tid - d] : 0;
        __syncthreads();
        ts[tid] += t;
        __syncthreads();
    }
    {
        int excl = ts[tid] - v;
        int node = base + tid;
        if (node <= N) off[node] = e0 + excl;
        if (node < N)  dinv[node] = rsqrtf((float)v + 1.0f);
        lofs[tid] = e0 + excl;
    }
    __syncthreads();
    for (int e = e0 + tid; e < e1; e += 512) {
        unsigned pk = epk[e];
        int pos = atomicAdd(&lofs[pk >> 17], 1);
        sse[pos] = (int)(pk & 0x1FFFF);
    }
}

// ---- GEMM1 (MFMA): th = fp16( (x @ W1) * dinv[row] )  [N,128]x[128,64] ----
__global__ __launch_bounds__(256) void gemm1_kernel(
    const float* __restrict__ x, const _Float16* __restrict__ w1t,
    const float* __restrict__ dinv, _Float16* __restrict__ th, int N) {
    __shared__ __align__(16) _Float16 xh[64 * ID];  // 16 KB, swizzled
    __shared__ __align__(16) _Float16 wh[HD * ID];  // 16 KB, swizzled
    int tid = threadIdx.x;
    int base = blockIdx.x * 64;
    #pragma unroll
    for (int it = 0; it < 4; ++it) {
        int idx = (it * 256 + tid) * 8;       // 0..8191 step 8
        int r = idx >> 7, c = idx & 127;
        f16x8 v = *(const f16x8*)&w1t[idx];
        *(f16x8*)&wh[r * ID + (c ^ ((r & 7) << 3))] = v;
    }
    #pragma unroll
    for (int it = 0; it < 4; ++it) {
        int idx = (it * 256 + tid) * 8;
        int r = idx >> 7, c = idx & 127;
        int row = base + r;
        f16x8 h;
        if (row < N) {
            float4 a = *(const float4*)&x[(size_t)row * ID + c];
            float4 b = *(const float4*)&x[(size_t)row * ID + c + 4];
            h[0] = (_Float16)a.x; h[1] = (_Float16)a.y;
            h[2] = (_Float16)a.z; h[3] = (_Float16)a.w;
            h[4] = (_Float16)b.x; h[5] = (_Float16)b.y;
            h[6] = (_Float16)b.z; h[7] = (_Float16)b.w;
        } else {
            #pragma unroll
            for (int j = 0; j < 8; ++j) h[j] = (_Float16)0.f;
        }
        *(f16x8*)&xh[r * ID + (c ^ ((r & 7) << 3))] = h;
    }
    __syncthreads();
    int lane = tid & 63, wv = tid >> 6;       // 4 waves; wave = 16 rows
    int lr = lane & 15, g = lane >> 4;
    f32x4 z = {0.f, 0.f, 0.f, 0.f};
    f32x4 acc[4] = {z, z, z, z};
    #pragma unroll
    for (int kk = 0; kk < 4; ++kk) {          // K = 128, 32 per step
        int kb = kk * 32 + g * 8;
        int ar = wv * 16 + lr;
        f16x8 af = *(const f16x8*)&xh[ar * ID + (kb ^ ((ar & 7) << 3))];
        #pragma unroll
        for (int ct = 0; ct < 4; ++ct) {
            int br = ct * 16 + lr;
            f16x8 bf = *(const f16x8*)&wh[br * ID + (kb ^ ((br & 7) << 3))];
            acc[ct] = __builtin_amdgcn_mfma_f32_16x16x32_f16(af, bf, acc[ct], 0, 0, 0);
        }
    }
    int r0 = base + wv * 16 + g * 4;
    #pragma unroll
    for (int j = 0; j < 4; ++j) {
        int row = r0 + j;
        if (row < N) {
            float dd = dinv[row];
            #pragma unroll
            for (int ct = 0; ct < 4; ++ct)
                th[(size_t)row * HD + ct * 16 + lr] = (_Float16)(acc[ct][j] * dd);
        }
    }
}

// ---- pull (R10 structure): one wave per node; 4 edges per wave-load
// (16 lanes x 8B each). th is dinv-premultiplied; output a stored fp16:
// a[d] = dinv[d] * ( sum_{s in N(d)} th'[s] + th'[d] )
__global__ __launch_bounds__(256) void pull_kernel(
    const int* __restrict__ off, const int* __restrict__ sse,
    const float* __restrict__ dinv, const _Float16* __restrict__ th,
    _Float16* __restrict__ a, int N) {
    int lane = threadIdx.x & 63;
    int w = (blockIdx.x * blockDim.x + threadIdx.x) >> 6;
    if (w >= N) return;
    int sub = lane >> 4;        // 0..3: which edge of the quad
    int fl  = lane & 15;        // feature-quad index
    const f16x4* th4 = (const f16x4*)th;    // row = 16 x f16x4
    int o0 = off[w], o1 = off[w + 1];
    float ax = 0.f, ay = 0.f, az = 0.f, aw = 0.f;
    int j = o0;
    while (j < o1) {
        int nb = min(64, o1 - j);
        int sidx = (lane < nb) ? sse[j + lane] : 0;   // one coalesced load
        int i = 0;
        for (; i + 15 < nb; i += 16) {                // 16 edges / iter, 4 loads
            int s0 = __shfl(sidx, i + sub);
            int s1 = __shfl(sidx, i + 4 + sub);
            int s2 = __shfl(sidx, i + 8 + sub);
            int s3 = __shfl(sidx, i + 12 + sub);
            f16x4 v0 = th4[(size_t)s0 * 16 + fl];
            f16x4 v1 = th4[(size_t)s1 * 16 + fl];
            f16x4 v2 = th4[(size_t)s2 * 16 + fl];
            f16x4 v3 = th4[(size_t)s3 * 16 + fl];
            ax += ((float)v0[0] + (float)v1[0]) + ((float)v2[0] + (float)v3[0]);
            ay += ((float)v0[1] + (float)v1[1]) + ((float)v2[1] + (float)v3[1]);
            az += ((float)v0[2] + (float)v1[2]) + ((float)v2[2] + (float)v3[2]);
            aw += ((float)v0[3] + (float)v1[3]) + ((float)v2[3] + (float)v3[3]);
        }
        for (; i < nb; i += 4) {                      // tail quads (predicated)
            int e = i + sub;
            int s = __shfl(sidx, (e < nb) ? e : (nb - 1));
            if (e < nb) {
                f16x4 v = th4[(size_t)s * 16 + fl];
                ax += (float)v[0]; ay += (float)v[1];
                az += (float)v[2]; aw += (float)v[3];
            }
        }
        j += nb;
    }
    // combine the 4 sub-group partials (lanes fl, fl+16, fl+32, fl+48)
    ax += __shfl_xor(ax, 16); ax += __shfl_xor(ax, 32);
    ay += __shfl_xor(ay, 16); ay += __shfl_xor(ay, 32);
    az += __shfl_xor(az, 16); az += __shfl_xor(az, 32);
    aw += __shfl_xor(aw, 16); aw += __shfl_xor(aw, 32);
    if (sub == 0) {
        f16x4 sv = th4[(size_t)w * 16 + fl];          // self-term (coalesced)
        float dd = dinv[w];
        f16x4 o;
        o[0] = (_Float16)(dd * (ax + (float)sv[0]));
        o[1] = (_Float16)(dd * (ay + (float)sv[1]));
        o[2] = (_Float16)(dd * (az + (float)sv[2]));
        o[3] = (_Float16)(dd * (aw + (float)sv[3]));
        ((f16x4*)a)[(size_t)w * 16 + fl] = o;         // 16 lanes x 8B = 128B
    }
}

// ---- GEMM2 (MFMA): th = fp16( (relu(a1+b1) @ W2) * dinv[row] ), a1 fp16 ----
__global__ __launch_bounds__(256) void gemm2_kernel(
    const _Float16* __restrict__ ain, const _Float16* __restrict__ w2t,
    const float* __restrict__ bias, const float* __restrict__ dinv,
    _Float16* __restrict__ th, int N) {
    __shared__ __align__(16) _Float16 ah[64 * HD];  // 8 KB, swizzled
    __shared__ __align__(16) _Float16 wh[HD * HD];  // 8 KB, swizzled
    int tid = threadIdx.x;
    int base = blockIdx.x * 64;
    #pragma unroll
    for (int it = 0; it < 2; ++it) {
        int idx = (it * 256 + tid) * 8;       // 0..4095 step 8
        int r = idx >> 6, c = idx & 63;
        f16x8 v = *(const f16x8*)&w2t[idx];
        *(f16x8*)&wh[r * HD + (c ^ ((r & 7) << 3))] = v;
    }
    #pragma unroll
    for (int it = 0; it < 2; ++it) {
        int idx = (it * 256 + tid) * 8;
        int r = idx >> 6, c = idx & 63;
        int row = base + r;
        f16x8 h;
        if (row < N) {
            f16x8 v = *(const f16x8*)&ain[(size_t)row * HD + c];
            #pragma unroll
            for (int jj = 0; jj < 8; ++jj)
                h[jj] = (_Float16)fmaxf((float)v[jj] + bias[c + jj], 0.f);
        } else {
            #pragma unroll
            for (int jj = 0; jj < 8; ++jj) h[jj] = (_Float16)0.f;
        }
        *(f16x8*)&ah[r * HD + (c ^ ((r & 7) << 3))] = h;
    }
    __syncthreads();
    int lane = tid & 63, wv = tid >> 6;
    int lr = lane & 15, g = lane >> 4;
    f32x4 z = {0.f, 0.f, 0.f, 0.f};
    f32x4 acc[4] = {z, z, z, z};
    #pragma unroll
    for (int kk = 0; kk < 2; ++kk) {          // K = 64, 32 per step
        int kb = kk * 32 + g * 8;
        int ar = wv * 16 + lr;
        f16x8 af = *(const f16x8*)&ah[ar * HD + (kb ^ ((ar & 7) << 3))];
        #pragma unroll
        for (int ct = 0; ct < 4; ++ct) {
            int br = ct * 16 + lr;
            f16x8 bf = *(const f16x8*)&wh[br * HD + (kb ^ ((br & 7) << 3))];
            acc[ct] = __builtin_amdgcn_mfma_f32_16x16x32_f16(af, bf, acc[ct], 0, 0, 0);
        }
    }
    int r0 = base + wv * 16 + g * 4;
    #pragma unroll
    for (int j = 0; j < 4; ++j) {
        int row = r0 + j;
        if (row < N) {
            float dd = dinv[row];
            #pragma unroll
            for (int ct = 0; ct < 4; ++ct)
                th[(size_t)row * HD + ct * 16 + lr] = (_Float16)(acc[ct][j] * dd);
        }
    }
}

// ---- head: out = (a2 + b2) @ Wc + bc   [N,64]x[64,16], a2 fp16 ----
__global__ __launch_bounds__(256) void final_kernel(
    const _Float16* __restrict__ ain, const float* __restrict__ b2,
    const float* __restrict__ Wc, const float* __restrict__ bc,
    float* __restrict__ out, int N) {
    __shared__ float Ws[HD * OD];     // 4 KB
    __shared__ float hs[16][HD + 1];  // padded
    int tid = threadIdx.x;
    for (int i = tid; i < HD * OD; i += 256) Ws[i] = Wc[i];
    int base = blockIdx.x * 16;
    for (int i = tid; i < 128; i += 256) {       // 16 rows x 8 f16x8 chunks
        int r = i >> 3, c = (i & 7) * 8;
        int row = base + r;
        if (row < N) {
            f16x8 v = *(const f16x8*)&ain[(size_t)row * HD + c];
            #pragma unroll
            for (int jj = 0; jj < 8; ++jj)
                hs[r][c + jj] = (float)v[jj] + b2[c + jj];
        } else {
            #pragma unroll
            for (int jj = 0; jj < 8; ++jj) hs[r][c + jj] = 0.f;
        }
    }
    __syncthreads();
    int col = tid & 15, r = tid >> 4;
    int row = base + r;
    if (row < N) {
        float acc = bc[col];
        #pragma unroll
        for (int k = 0; k < HD; ++k)
            acc += hs[r][k] * Ws[k * OD + col];
        out[(size_t)row * OD + col] = acc;
    }
}

extern "C" void kernel_launch(void* const* d_in, const int* in_sizes, int n_in,
                              void* d_out, int out_size, void* d_ws, size_t ws_size,
                              hipStream_t stream) {
    const float* x  = (const float*)d_in[0];
    const int*   ei = (const int*)d_in[1];   // [2,E] flat int32
    const float* W1 = (const float*)d_in[2];
    const float* b1 = (const float*)d_in[3];
    const float* W2 = (const float*)d_in[4];
    const float* b2 = (const float*)d_in[5];
    const float* Wc = (const float*)d_in[6];
    const float* bc = (const float*)d_in[7];
    float* out = (float*)d_out;

    int N = in_sizes[0] / ID;   // 100000
    int E = in_sizes[1] / 2;    // 1600000 (multiple of 4)
    const int* src = ei;
    const int* dst = ei + E;
    int K = (N + RB - 1) / RB;  // 196 coarse buckets (K <= KMAX)
    int Npad = (N + 63) & ~63;

    char* p = (char*)d_ws;
    int*      cnt    = (int*)p;      p += KMAX * 4;
    int*      coff   = (int*)p;      p += (KMAX + 4) * 4;
    int*      cursor = (int*)p;      p += KMAX * 4;
    float*    dinv   = (float*)p;    p += (size_t)Npad * 4;
    int*      off    = (int*)p;      p += (size_t)(Npad + RB) * 4;
    _Float16* w1t    = (_Float16*)p; p += (size_t)HD * ID * 2;  // [64][128]
    _Float16* w2t    = (_Float16*)p; p += (size_t)HD * HD * 2;  // [64][64]
    unsigned* epk    = (unsigned*)p; p += (size_t)E * 4;        // bucketed edges
    int*      sse    = (int*)p;      p += (size_t)E * 4;        // CSR src
    _Float16* th     = (_Float16*)p; p += (size_t)N * HD * 2;   // dinv-premult msgs
    _Float16* a1     = (_Float16*)p; p += (size_t)N * HD * 2;   // agg out, fp16

    hipMemsetAsync(cnt, 0, (size_t)K * sizeof(int), stream);

    // dense CSR build (shared by both layers) + weight prep
    passA_kernel<<<512, 256, 0, stream>>>((const int4*)dst, cnt, E / 4, K);
    prepscan_kernel<<<33, 256, 0, stream>>>(W1, W2, w1t, w2t, cnt, coff, cursor, K, E);
    passB_kernel<<<(E + CHUNK - 1) / CHUNK, 256, 0, stream>>>(src, dst, cursor, epk, E);
    sortB_kernel<<<K, RB, 0, stream>>>(coff, epk, sse, off, dinv, N);

    int pgrid = (N * 64 + 255) / 256;

    // layer 1
    gemm1_kernel<<<(N + 63) / 64, 256, 0, stream>>>(x, w1t, dinv, th, N);
    pull_kernel<<<pgrid, 256, 0, stream>>>(off, sse, dinv, th, a1, N);

    // layer 2
    gemm2_kernel<<<(N + 63) / 64, 256, 0, stream>>>(a1, w2t, b1, dinv, th, N);
    pull_kernel<<<pgrid, 256, 0, stream>>>(off, sse, dinv, th, a1, N);

    // head
    final_kernel<<<(N + 15) / 16, 256, 0, stream>>>(a1, b2, Wc, bc, out, N);
}